// Round 12
// baseline (374.331 us; speedup 1.0000x reference)
//
#include <hip/hip_runtime.h>
#include <cstdint>
#include <cstddef>

#define TEXTD 768
#define VISD  512
#define AUDD  128

__device__ __forceinline__ float wred_sum(float v){
  #pragma unroll
  for (int m = 32; m >= 1; m >>= 1) v += __shfl_xor(v, m, 64);
  return v;
}
__device__ __forceinline__ int wred_sumi(int v){
  #pragma unroll
  for (int m = 32; m >= 1; m >>= 1) v += __shfl_xor(v, m, 64);
  return v;
}
__device__ __forceinline__ float wred_max(float v){
  #pragma unroll
  for (int m = 32; m >= 1; m >>= 1) v = fmaxf(v, __shfl_xor(v, m, 64));
  return v;
}

// ---------------- merged front: type-bucket counts + edge-degree atomics + bstart ----------------
// grid covers E (largest). deg must be ZEROED before (memset); self-loop +1 added in the scan.
__global__ __launch_bounds__(256) void k_front(const int* __restrict__ ntype,
    const int* __restrict__ batch, const int* __restrict__ ei,
    int nN, int E, int B, int nblk,
    int* __restrict__ bcnt, int* __restrict__ deg, int* __restrict__ bstart){
  int b = blockIdx.x;
  int t = threadIdx.x;
  int i = b*256 + t;
  int lane = t & 63, w = t >> 6;
  // (a) type-bucket counts (blocks < nblk)
  int ty = (b < nblk && i < nN) ? ntype[i] : -1;
  __shared__ int wc[4][3];
  #pragma unroll
  for (int h = 0; h < 3; h++){
    unsigned long long m = __ballot(ty == h);
    if (lane == 0) wc[w][h] = __popcll(m);
  }
  __syncthreads();
  if (b < nblk && t < 3){
    int h = t;
    bcnt[h*nblk + b] = wc[0][h] + wc[1][h] + wc[2][h] + wc[3][h];
  }
  // (b) bstart boundary-detect (sorted batch)
  if (i < nN){
    int prev = (i == 0) ? -1 : batch[i-1];
    int cur  = batch[i];
    for (int bb = prev+1; bb <= cur; bb++) bstart[bb] = i;
  } else if (i == nN){
    int last = batch[nN-1];
    for (int bb = last+1; bb <= B; bb++) bstart[bb] = nN;
  }
  // (c) edge-degree atomics
  if (i < E) atomicAdd(&deg[ei[E + i]], 1);
}

// ---------------- bscan + afold merged (one block) ----------------
__global__ __launch_bounds__(1024) void k_bscan_afold(const int* __restrict__ bcnt, int nblk, int nN,
    int* __restrict__ boff, int* __restrict__ toff, int* __restrict__ tcnt,
    const float* __restrict__ W1, const float* __restrict__ a1s, const float* __restrict__ a1d,
    float* __restrict__ wfs, float* __restrict__ wfd){
  int t = threadIdx.x;
  // afold on t<256 (no barriers inside)
  if (t < 256){
    int k = t & 63, h = t >> 6;
    const float* wr = W1 + (size_t)k*256 + h*64;
    const float* as = a1s + h*64;
    const float* ad = a1d + h*64;
    float s = 0.f, d = 0.f;
    for (int c = 0; c < 64; c += 4){
      float4 wv = *reinterpret_cast<const float4*>(wr + c);
      float4 sa = *reinterpret_cast<const float4*>(as + c);
      float4 da = *reinterpret_cast<const float4*>(ad + c);
      s += wv.x*sa.x + wv.y*sa.y + wv.z*sa.z + wv.w*sa.w;
      d += wv.x*da.x + wv.y*da.y + wv.z*da.z + wv.w*da.w;
    }
    wfs[k*4 + h] = s;
    wfd[k*4 + h] = d;
  }
  // bscan
  __shared__ int s[2048];          // supports nblk*3 <= 2048
  int n3 = nblk*3;
  for (int i = t; i < n3; i += 1024) s[i] = bcnt[i];
  __syncthreads();
  if (t == 0){
    int run = 0;
    for (int i = 0; i < n3; i++){ int v = s[i]; s[i] = run; run += v; }
  }
  __syncthreads();
  for (int i = t; i < n3; i += 1024) boff[i] = s[i];
  if (t == 0){
    toff[0] = 0;         toff[1] = s[nblk];           toff[2] = s[2*nblk];
    tcnt[0] = s[nblk];   tcnt[1] = s[2*nblk]-s[nblk]; tcnt[2] = nN - s[2*nblk];
  }
}

__global__ __launch_bounds__(256) void k_bscatter(const int* __restrict__ ntype, int nN, int nblk,
                                                  const int* __restrict__ boff, int* __restrict__ order){
  int b = blockIdx.x;
  int i = b*256 + threadIdx.x;
  int lane = threadIdx.x & 63, w = threadIdx.x >> 6;
  int ty = (i < nN) ? ntype[i] : -1;
  __shared__ int wc[4][3];
  __shared__ int woff[4][3];
  unsigned long long masks[3];
  #pragma unroll
  for (int t = 0; t < 3; t++){
    masks[t] = __ballot(ty == t);
    if (lane == 0) wc[w][t] = __popcll(masks[t]);
  }
  __syncthreads();
  if (threadIdx.x < 3){
    int t = threadIdx.x, run = 0;
    #pragma unroll
    for (int ww = 0; ww < 4; ww++){ woff[ww][t] = run; run += wc[ww][t]; }
  }
  __syncthreads();
  if (ty >= 0){
    int r = __popcll(masks[ty] & ((1ULL << lane) - 1ULL));
    int pos = boff[ty*nblk + b] + woff[w][ty] + r;
    order[pos] = i;
  }
}

// ---------------- multi-block scan over (deg[i]+1) ----------------
__global__ __launch_bounds__(1024) void k_sumblk(const int* __restrict__ deg, int n,
                                                 int* __restrict__ bsum){
  int b = blockIdx.x;
  int i = b*1024 + threadIdx.x;
  int lane = threadIdx.x & 63, w = threadIdx.x >> 6;
  __shared__ int wsum[16];
  int v = (i < n) ? deg[i] + 1 : 0;     // +1 = self-loop
  v = wred_sumi(v);
  if (lane == 0) wsum[w] = v;
  __syncthreads();
  if (threadIdx.x == 0){
    int s = 0;
    #pragma unroll
    for (int k = 0; k < 16; k++) s += wsum[k];
    bsum[b] = s;
  }
}
__global__ void k_sumscan(const int* __restrict__ bsum, int nsb, int* __restrict__ bsoff){
  if (threadIdx.x == 0){
    int run = 0;
    for (int i = 0; i < nsb; i++){ bsoff[i] = run; run += bsum[i]; }
    bsoff[nsb] = run;
  }
}
__global__ __launch_bounds__(1024) void k_offw(int* __restrict__ deg, const int* __restrict__ bsoff,
                                               int n, int* __restrict__ off){
  int b = blockIdx.x;
  int i = b*1024 + threadIdx.x;
  int t = threadIdx.x, lane = t & 63, w = t >> 6;
  __shared__ int wsum[16];
  int v = (i < n) ? deg[i] + 1 : 0;     // +1 = self-loop
  int orig = v;
  #pragma unroll
  for (int o = 1; o < 64; o <<= 1){ int u = __shfl_up(v, o, 64); if (lane >= o) v += u; }
  if (lane == 63) wsum[w] = v;
  __syncthreads();
  if (t < 16){
    int xv = wsum[t];
    #pragma unroll
    for (int o = 1; o < 16; o <<= 1){ int u = __shfl_up(xv, o, 16); if (t >= o) xv += u; }
    wsum[t] = xv;
  }
  __syncthreads();
  int wbase = (w == 0) ? 0 : wsum[w-1];
  int e = bsoff[b] + v + wbase - orig;     // exclusive
  if (i < n){ off[i] = e; deg[i] = e; }    // deg now = pos (row start)
  if (b == 0 && t == 0) off[n] = bsoff[gridDim.x];
}
__global__ void k_scatter(const int* __restrict__ ei, int E, int nN,
                          int* __restrict__ pos, int* __restrict__ csr_src){
  int i = blockIdx.x*blockDim.x + threadIdx.x;
  int total = E + nN;
  if (i >= total) return;
  int s, d;
  if (i < E){ s = ei[i]; d = ei[E + i]; } else { s = i - E; d = s; }
  int p = atomicAdd(&pos[d], 1);
  csr_src[p] = s;
}

// ---------------- projection: 128-node x 64-chan tile, 8x4 regs/thread; fused alpha1 ----------
__global__ __launch_bounds__(256) void k_projgemm(const float* __restrict__ x,
    const int* __restrict__ order, const int* __restrict__ toff, const int* __restrict__ tcnt,
    const float* __restrict__ Wt, const float* __restrict__ bt,
    const float* __restrict__ Wv, const float* __restrict__ bv,
    const float* __restrict__ Wa, const float* __restrict__ ba,
    const float* __restrict__ wfs, const float* __restrict__ wfd,
    float* __restrict__ h0, float* __restrict__ as1, float* __restrict__ ad1){
  int ty = blockIdx.y;
  int cnt = tcnt[ty];
  int tile = blockIdx.x;
  if (tile*128 >= cnt) return;
  const float* W; const float* bias; int dim;
  if (ty == 0)      { W = Wt; bias = bt; dim = TEXTD; }
  else if (ty == 1) { W = Wv; bias = bv; dim = VISD; }
  else              { W = Wa; bias = ba; dim = AUDD; }
  int off = toff[ty];

  __shared__ float xsT[64][136];   // [k][node 0..127] (+pad)
  __shared__ float ws [64][68];    // [k][chan]
  __shared__ int   nid[128];

  int t = threadIdx.x;
  if (t < 128){
    int idx = tile*128 + t;
    nid[t] = (idx < cnt) ? order[off + idx] : -1;
  }
  __syncthreads();

  int row = t >> 1, half = t & 1;               // x staging: 2 threads/row, 8 f4 each
  int ndr = nid[row];
  const float* xrow = x + (size_t)(ndr < 0 ? 0 : ndr) * TEXTD;
  int wrow = t >> 2, wu = t & 3;                // W staging
  int ng = t & 15, cg = t >> 4;                 // compute: 8 nodes x 4 chans
  int n0 = ng*8, c0 = cg*4;
  float acc[8][4] = {};

  for (int k0 = 0; k0 < dim; k0 += 64){
    __syncthreads();
    #pragma unroll
    for (int j = 0; j < 8; j++){
      int f4 = half*8 + j;
      float4 v = *reinterpret_cast<const float4*>(xrow + k0 + f4*4);
      xsT[f4*4+0][row] = v.x; xsT[f4*4+1][row] = v.y;
      xsT[f4*4+2][row] = v.z; xsT[f4*4+3][row] = v.w;
    }
    #pragma unroll
    for (int j = 0; j < 4; j++){
      int f4 = j*4 + wu;
      float4 v = *reinterpret_cast<const float4*>(W + (size_t)(k0 + wrow)*64 + f4*4);
      *reinterpret_cast<float4*>(&ws[wrow][f4*4]) = v;
    }
    __syncthreads();
    #pragma unroll 4
    for (int kk = 0; kk < 64; kk++){
      float4 x0 = *reinterpret_cast<const float4*>(&xsT[kk][n0]);
      float4 x1 = *reinterpret_cast<const float4*>(&xsT[kk][n0+4]);
      float4 wv = *reinterpret_cast<const float4*>(&ws[kk][c0]);
      float xa[8] = {x0.x,x0.y,x0.z,x0.w, x1.x,x1.y,x1.z,x1.w};
      float wb[4] = {wv.x,wv.y,wv.z,wv.w};
      #pragma unroll
      for (int i = 0; i < 8; i++)
        #pragma unroll
        for (int j = 0; j < 4; j++)
          acc[i][j] += xa[i] * wb[j];
    }
  }

  float4 b4 = *reinterpret_cast<const float4*>(bias + c0);
  float bb[4] = {b4.x, b4.y, b4.z, b4.w};
  #pragma unroll
  for (int i = 0; i < 8; i++){
    int nd = nid[n0 + i];
    if (nd >= 0){
      float4 o4 = make_float4(acc[i][0]+bb[0], acc[i][1]+bb[1], acc[i][2]+bb[2], acc[i][3]+bb[3]);
      *reinterpret_cast<float4*>(h0 + (size_t)nd*64 + c0) = o4;
    }
  }

  // -------- fused alpha1 (two passes through xsT scratch: s then d) --------
  float* part = &xsT[0][0];   // 8704 floats >= 128*64
  float4 wsv[4], wdv[4];
  #pragma unroll
  for (int j = 0; j < 4; j++){
    wsv[j] = *reinterpret_cast<const float4*>(wfs + (c0+j)*4);
    wdv[j] = *reinterpret_cast<const float4*>(wfd + (c0+j)*4);
  }
  __syncthreads();
  #pragma unroll
  for (int i = 0; i < 8; i++){
    float hv[4];
    #pragma unroll
    for (int j = 0; j < 4; j++) hv[j] = acc[i][j] + bb[j];
    int nidx = (n0 + i)*64 + cg*4;
    part[nidx+0] = hv[0]*wsv[0].x + hv[1]*wsv[1].x + hv[2]*wsv[2].x + hv[3]*wsv[3].x;
    part[nidx+1] = hv[0]*wsv[0].y + hv[1]*wsv[1].y + hv[2]*wsv[2].y + hv[3]*wsv[3].y;
    part[nidx+2] = hv[0]*wsv[0].z + hv[1]*wsv[1].z + hv[2]*wsv[2].z + hv[3]*wsv[3].z;
    part[nidx+3] = hv[0]*wsv[0].w + hv[1]*wsv[1].w + hv[2]*wsv[2].w + hv[3]*wsv[3].w;
  }
  __syncthreads();
  if (t < 128){
    int nd = nid[t];
    if (nd >= 0){
      float s[4] = {0,0,0,0};
      #pragma unroll
      for (int g = 0; g < 16; g++)
        #pragma unroll
        for (int h = 0; h < 4; h++) s[h] += part[t*64 + g*4 + h];
      *reinterpret_cast<float4*>(as1 + (size_t)nd*4) = make_float4(s[0],s[1],s[2],s[3]);
    }
  }
  __syncthreads();
  #pragma unroll
  for (int i = 0; i < 8; i++){
    float hv[4];
    #pragma unroll
    for (int j = 0; j < 4; j++) hv[j] = acc[i][j] + bb[j];
    int nidx = (n0 + i)*64 + cg*4;
    part[nidx+0] = hv[0]*wdv[0].x + hv[1]*wdv[1].x + hv[2]*wdv[2].x + hv[3]*wdv[3].x;
    part[nidx+1] = hv[0]*wdv[0].y + hv[1]*wdv[1].y + hv[2]*wdv[2].y + hv[3]*wdv[3].y;
    part[nidx+2] = hv[0]*wdv[0].z + hv[1]*wdv[1].z + hv[2]*wdv[2].z + hv[3]*wdv[3].z;
    part[nidx+3] = hv[0]*wdv[0].w + hv[1]*wdv[1].w + hv[2]*wdv[2].w + hv[3]*wdv[3].w;
  }
  __syncthreads();
  if (t < 128){
    int nd = nid[t];
    if (nd >= 0){
      float d[4] = {0,0,0,0};
      #pragma unroll
      for (int g = 0; g < 16; g++)
        #pragma unroll
        for (int h = 0; h < 4; h++) d[h] += part[t*64 + g*4 + h];
      *reinterpret_cast<float4*>(ad1 + (size_t)nd*4) = make_float4(d[0],d[1],d[2],d[3]);
    }
  }
}

// ---------------- conv1 aggregate over h0: 4 waves/block, wave-private LDS, NO barriers -------
__global__ __launch_bounds__(256) void k_gat1z(const int* __restrict__ off, const int* __restrict__ srcs,
    const float* __restrict__ as1, const float* __restrict__ ad1,
    const float* __restrict__ h0, float* __restrict__ z, int nN){
  int w = threadIdx.x >> 6, L = threadIdx.x & 63;
  int n = blockIdx.x*4 + w;
  __shared__ int   s_src[4][64];
  __shared__ float s_p[4][64][4];
  if (n >= nN) return;
  int hL = L >> 4, c4 = (L & 15)*4;
  float ad[4];
  { float4 a = *reinterpret_cast<const float4*>(ad1 + (size_t)n*4);
    ad[0]=a.x; ad[1]=a.y; ad[2]=a.z; ad[3]=a.w; }
  int s0 = off[n], s1 = off[n+1];
  float m[4] = {-1e30f,-1e30f,-1e30f,-1e30f};
  float den[4] = {0.f,0.f,0.f,0.f};
  float4 acc = make_float4(0.f,0.f,0.f,0.f);
  for (int base = s0; base < s1; base += 64){
    int e = base + L;
    int cl = min(64, s1 - base);
    bool valid = (e < s1);
    int sv = 0; float v[4];
    if (valid){
      sv = srcs[e];
      float4 a = *reinterpret_cast<const float4*>(as1 + (size_t)sv*4);
      float av[4] = {a.x,a.y,a.z,a.w};
      #pragma unroll
      for (int h = 0; h < 4; h++){ float tt = av[h] + ad[h]; v[h] = (tt>0.f)?tt:0.2f*tt; }
    } else {
      #pragma unroll
      for (int h = 0; h < 4; h++) v[h] = -1e30f;
    }
    float sc[4], pv[4];
    #pragma unroll
    for (int h = 0; h < 4; h++){
      float cm = wred_max(v[h]);
      float mn = fmaxf(m[h], cm);
      sc[h] = __expf(m[h] - mn);
      m[h] = mn;
      float p = valid ? __expf(v[h] - mn) : 0.f;
      den[h] = den[h]*sc[h] + wred_sum(p);
      pv[h] = p;
    }
    { float s4 = sc[hL]; acc.x*=s4; acc.y*=s4; acc.z*=s4; acc.w*=s4; }
    if (valid){
      s_src[w][L] = sv;
      *reinterpret_cast<float4*>(&s_p[w][L][0]) = make_float4(pv[0],pv[1],pv[2],pv[3]);
    }
    #pragma unroll 4
    for (int e2 = 0; e2 < cl; e2++){
      int sr = s_src[w][e2];
      float pp = s_p[w][e2][hL];
      float4 hv = *reinterpret_cast<const float4*>(h0 + (size_t)sr*64 + c4);
      acc.x += pp*hv.x; acc.y += pp*hv.y; acc.z += pp*hv.z; acc.w += pp*hv.w;
    }
  }
  float dl = den[hL] + 1e-16f;
  *reinterpret_cast<float4*>(z + (size_t)n*256 + hL*64 + c4) =
      make_float4(acc.x/dl, acc.y/dl, acc.z/dl, acc.w/dl);
}

// ---------------- FUSED conv1-lin + conv2-lin:  h2 = ELU(z_q @ W1_q + b1) @ W2 ; alpha2 --------
__global__ __launch_bounds__(256) void k_fuse12(const float* __restrict__ z,
    const float* __restrict__ W1, const float* __restrict__ b1,
    const float* __restrict__ W2, const float* __restrict__ a2s, const float* __restrict__ a2d,
    float* __restrict__ h2, float* __restrict__ as2, float* __restrict__ ad2, int nN){
  int base = blockIdx.x*64;
  __shared__ float xsT[64][68];
  __shared__ float ws [64][68];
  __shared__ float sPart[16][64];
  __shared__ float dPart[16][64];

  int t = threadIdx.x;
  int row = t >> 2, fq = t & 3;
  int ndl = base + row; if (ndl >= nN) ndl = nN - 1;
  int n0 = (t & 15)*4, c0 = (t >> 4)*4, qg = t >> 4;
  float h2acc[4][4] = {};

  for (int q = 0; q < 4; q++){
    __syncthreads();
    {
      const float* zr = z + (size_t)ndl*256 + q*64;
      #pragma unroll
      for (int j = 0; j < 4; j++){
        int f4 = j*4 + fq;
        float4 v = *reinterpret_cast<const float4*>(zr + f4*4);
        xsT[f4*4+0][row] = v.x; xsT[f4*4+1][row] = v.y;
        xsT[f4*4+2][row] = v.z; xsT[f4*4+3][row] = v.w;
      }
    }
    #pragma unroll
    for (int j = 0; j < 4; j++){
      int f4 = j*4 + fq;
      float4 v = *reinterpret_cast<const float4*>(W1 + (size_t)row*256 + q*64 + f4*4);
      *reinterpret_cast<float4*>(&ws[row][f4*4]) = v;
    }
    __syncthreads();
    float racc[4][4] = {};
    #pragma unroll 8
    for (int k = 0; k < 64; k++){
      float4 xv = *reinterpret_cast<const float4*>(&xsT[k][n0]);
      float4 wv = *reinterpret_cast<const float4*>(&ws[k][c0]);
      float xa[4] = {xv.x, xv.y, xv.z, xv.w};
      float wb[4] = {wv.x, wv.y, wv.z, wv.w};
      #pragma unroll
      for (int i = 0; i < 4; i++)
        #pragma unroll
        for (int j = 0; j < 4; j++)
          racc[i][j] += xa[i] * wb[j];
    }
    {
      float4 b4 = *reinterpret_cast<const float4*>(b1 + q*64 + c0);
      float bb[4] = {b4.x, b4.y, b4.z, b4.w};
      #pragma unroll
      for (int i = 0; i < 4; i++)
        #pragma unroll
        for (int j = 0; j < 4; j++){
          float u = racc[i][j] + bb[j];
          racc[i][j] = (u > 0.f) ? u : expm1f(u);
        }
    }
    __syncthreads();
    #pragma unroll
    for (int i = 0; i < 4; i++)
      #pragma unroll
      for (int j = 0; j < 4; j++)
        xsT[c0+j][n0+i] = racc[i][j];
    #pragma unroll
    for (int j = 0; j < 4; j++){
      int f4 = j*4 + fq;
      float4 v = *reinterpret_cast<const float4*>(W2 + (size_t)(q*64 + row)*64 + f4*4);
      *reinterpret_cast<float4*>(&ws[row][f4*4]) = v;
    }
    __syncthreads();
    #pragma unroll 8
    for (int k = 0; k < 64; k++){
      float4 xv = *reinterpret_cast<const float4*>(&xsT[k][n0]);
      float4 wv = *reinterpret_cast<const float4*>(&ws[k][c0]);
      float xa[4] = {xv.x, xv.y, xv.z, xv.w};
      float wb[4] = {wv.x, wv.y, wv.z, wv.w};
      #pragma unroll
      for (int i = 0; i < 4; i++)
        #pragma unroll
        for (int j = 0; j < 4; j++)
          h2acc[i][j] += xa[i] * wb[j];
    }
  }

  float avs[4], avd[4];
  {
    float4 s4 = *reinterpret_cast<const float4*>(a2s + c0);
    float4 d4 = *reinterpret_cast<const float4*>(a2d + c0);
    avs[0]=s4.x; avs[1]=s4.y; avs[2]=s4.z; avs[3]=s4.w;
    avd[0]=d4.x; avd[1]=d4.y; avd[2]=d4.z; avd[3]=d4.w;
  }
  #pragma unroll
  for (int i = 0; i < 4; i++){
    int nd = base + n0 + i;
    float sp = h2acc[i][0]*avs[0] + h2acc[i][1]*avs[1] + h2acc[i][2]*avs[2] + h2acc[i][3]*avs[3];
    float dp = h2acc[i][0]*avd[0] + h2acc[i][1]*avd[1] + h2acc[i][2]*avd[2] + h2acc[i][3]*avd[3];
    sPart[qg][n0+i] = sp;
    dPart[qg][n0+i] = dp;
    if (nd < nN){
      float4 o4 = make_float4(h2acc[i][0], h2acc[i][1], h2acc[i][2], h2acc[i][3]);
      *reinterpret_cast<float4*>(h2 + (size_t)nd*64 + c0) = o4;
    }
  }
  __syncthreads();
  if (t < 64){
    int nd = base + t;
    if (nd < nN){
      float s = 0.f, d = 0.f;
      #pragma unroll
      for (int g = 0; g < 16; g++){ s += sPart[g][t]; d += dPart[g][t]; }
      as2[nd] = s;
      ad2[nd] = d;
    }
  }
}

// ---------------- conv2 aggregate + b2 -> g2[n][64] (no atomics; exec-mask-safe shfl) ----------
__global__ __launch_bounds__(256) void k_gat2v(const int* __restrict__ off, const int* __restrict__ srcs,
    const float* __restrict__ as2, const float* __restrict__ ad2,
    const float* __restrict__ h2, const float* __restrict__ b2,
    float* __restrict__ g2, int nN){
  int w = threadIdx.x >> 6, L = threadIdx.x & 63;
  int n = blockIdx.x*4 + w;
  if (n >= nN) return;
  int g = L >> 4, c4 = (L & 15)*4;
  float ad = ad2[n];
  int s0 = off[n], s1 = off[n+1];
  float m = -1e30f, den = 0.f;
  float4 acc = make_float4(0.f,0.f,0.f,0.f);
  for (int base = s0; base < s1; base += 64){
    int e = base + L;
    int cl = min(64, s1 - base);
    bool valid = (e < s1);
    int sv = 0; float v = -1e30f;
    if (valid){
      sv = srcs[e];
      float tt = as2[sv] + ad;
      v = (tt>0.f)?tt:0.2f*tt;
    }
    float cm = wred_max(v);
    float mn = fmaxf(m, cm);
    float sc = __expf(m - mn);
    m = mn;
    float p = valid ? __expf(v - mn) : 0.f;
    den = den*sc + wred_sum(p);
    acc.x*=sc; acc.y*=sc; acc.z*=sc; acc.w*=sc;
    int iters = (cl + 3) >> 2;          // wave-uniform trip count
    for (int it = 0; it < iters; ++it){
      int e2   = it*4 + g;
      int esrc = (e2 < cl) ? e2 : (cl - 1);   // clamp -> source lane always active
      int   sr = __shfl(sv, esrc, 64);
      float pp = __shfl(p,  esrc, 64);
      if (e2 < cl){
        float4 hv = *reinterpret_cast<const float4*>(h2 + (size_t)sr*64 + c4);
        acc.x += pp*hv.x; acc.y += pp*hv.y; acc.z += pp*hv.z; acc.w += pp*hv.w;
      }
    }
  }
  #pragma unroll
  for (int s = 16; s <= 32; s <<= 1){
    acc.x += __shfl_xor(acc.x, s, 64);
    acc.y += __shfl_xor(acc.y, s, 64);
    acc.z += __shfl_xor(acc.z, s, 64);
    acc.w += __shfl_xor(acc.w, s, 64);
  }
  float dl = den + 1e-16f;
  if (L < 16){
    float4 b4 = *reinterpret_cast<const float4*>(b2 + c4);
    float4 o4 = make_float4(acc.x/dl + b4.x, acc.y/dl + b4.y,
                            acc.z/dl + b4.z, acc.w/dl + b4.w);
    *reinterpret_cast<float4*>(g2 + (size_t)n*64 + c4) = o4;
  }
}

// ---------------- pool: out[b] = mean(g2 rows) @ Wl + bl ----------------
__global__ __launch_bounds__(64) void k_pool(const float* __restrict__ g2, const int* __restrict__ bstart,
    const float* __restrict__ Wl, const float* __restrict__ bl, float* __restrict__ out, int B){
  int b = blockIdx.x, c = threadIdx.x;
  int r0 = bstart[b], r1 = bstart[b+1];
  float s = 0.f;
  int i = r0;
  for (; i + 4 <= r1; i += 4){
    s += g2[(size_t)(i+0)*64 + c];
    s += g2[(size_t)(i+1)*64 + c];
    s += g2[(size_t)(i+2)*64 + c];
    s += g2[(size_t)(i+3)*64 + c];
  }
  for (; i < r1; i++) s += g2[(size_t)i*64 + c];
  float g = s / fmaxf((float)(r1 - r0), 1.f);
  float v = wred_sum(g * Wl[c]);
  if (c == 0) out[b] = v + bl[0];
}

extern "C" void kernel_launch(void* const* d_in, const int* in_sizes, int n_in,
                              void* d_out, int out_size, void* d_ws, size_t ws_size,
                              hipStream_t stream){
  const float* x    = (const float*)d_in[0];
  const int*   ntyp = (const int*)  d_in[1];
  const int*   ei   = (const int*)  d_in[2];
  const int*   batch= (const int*)  d_in[3];
  const float* Wt = (const float*)d_in[4];
  const float* bt = (const float*)d_in[5];
  const float* Wv = (const float*)d_in[6];
  const float* bv = (const float*)d_in[7];
  const float* Wa = (const float*)d_in[8];
  const float* ba = (const float*)d_in[9];
  const float* W1 = (const float*)d_in[10];
  const float* a1s= (const float*)d_in[11];
  const float* a1d= (const float*)d_in[12];
  const float* b1 = (const float*)d_in[13];
  const float* W2 = (const float*)d_in[14];
  const float* a2s= (const float*)d_in[15];
  const float* a2d= (const float*)d_in[16];
  const float* b2 = (const float*)d_in[17];
  const float* Wl = (const float*)d_in[18];
  const float* bl = (const float*)d_in[19];

  const int N = in_sizes[1];
  const int E = in_sizes[2] / 2;
  const int B = out_size;
  const int nblk = (N + 255)/256;
  const int nsb  = (N + 1023)/1024;

  char* ws = (char*)d_ws;
  size_t o = 0;
  auto alloc = [&](size_t bytes) -> void* {
    void* p = ws + o;
    o = (o + bytes + 255) & ~(size_t)255;
    return p;
  };
  int*   csr_off = (int*)  alloc((size_t)(N+1)*4);
  int*   pos     = (int*)  alloc((size_t)N*4);     // doubles as deg
  int*   csr_src = (int*)  alloc((size_t)(E+N)*4);
  float* as1     = (float*)alloc((size_t)N*4*4);
  float* ad1     = (float*)alloc((size_t)N*4*4);
  float* h0      = (float*)alloc((size_t)N*64*4);
  float* zbuf    = (float*)alloc((size_t)N*256*4);
  int*   bstart  = (int*)  alloc((size_t)(B+1)*4);
  int*   bcnt    = (int*)  alloc((size_t)nblk*3*4);
  int*   boff    = (int*)  alloc((size_t)nblk*3*4);
  int*   toff    = (int*)  alloc(3*4);
  int*   tcnt    = (int*)  alloc(3*4);
  int*   order   = (int*)  alloc((size_t)N*4);
  float* wfs     = (float*)alloc(256*4);
  float* wfd     = (float*)alloc(256*4);
  int*   bsum    = (int*)  alloc((size_t)nsb*4);
  int*   bsoff   = (int*)  alloc((size_t)(nsb+1)*4);
  // aliases: h2 reuses h0 (dead after k_gat1z); alpha2 reuses alpha1 (dead after k_gat1z);
  //          g2 reuses zbuf (dead after k_fuse12)
  float* h2  = h0;
  float* as2 = as1;
  float* ad2 = ad1;
  float* g2  = zbuf;

  // deg must be zero before edge atomics (self-loop +1 is added in the scan)
  hipMemsetAsync(pos, 0, (size_t)N*4, stream);

  // merged front: bucket counts + edge-degree atomics + bstart
  k_front<<<(E + 255)/256, 256, 0, stream>>>(ntyp, batch, ei, N, E, B, nblk, bcnt, pos, bstart);
  k_bscan_afold<<<1, 1024, 0, stream>>>(bcnt, nblk, N, boff, toff, tcnt, W1, a1s, a1d, wfs, wfd);
  k_bscatter<<<nblk, 256, 0, stream>>>(ntyp, N, nblk, boff, order);

  // CSR scan (over deg+1) + scatter
  k_sumblk  <<<nsb, 1024, 0, stream>>>(pos, N, bsum);
  k_sumscan <<<1, 64, 0, stream>>>(bsum, nsb, bsoff);
  k_offw    <<<nsb, 1024, 0, stream>>>(pos, bsoff, N, csr_off);
  k_scatter <<<(E + N + 255)/256, 256, 0, stream>>>(ei, E, N, pos, csr_src);

  // projection + fused alpha1 (128-node tiles)
  {
    dim3 g((N + 127)/128, 3);
    k_projgemm<<<g, 256, 0, stream>>>(x, order, toff, tcnt, Wt, bt, Wv, bv, Wa, ba,
                                      wfs, wfd, h0, as1, ad1);
  }

  // conv1 aggregate -> fused (per-head GEMM + ELU + lin2 + alpha2)
  k_gat1z <<<(N + 3)/4, 256, 0, stream>>>(csr_off, csr_src, as1, ad1, h0, zbuf, N);
  k_fuse12<<<(N + 63)/64, 256, 0, stream>>>(zbuf, W1, b1, W2, a2s, a2d, h2, as2, ad2, N);

  // conv2 + pooling
  k_gat2v<<<(N + 3)/4, 256, 0, stream>>>(csr_off, csr_src, as2, ad2, h2, b2, g2, N);
  k_pool<<<B, 64, 0, stream>>>(g2, bstart, Wl, bl, (float*)d_out, B);
}

// Round 13
// 348.677 us; speedup vs baseline: 1.0736x; 1.0736x over previous
//
#include <hip/hip_runtime.h>
#include <cstdint>
#include <cstddef>

#define TEXTD 768
#define VISD  512
#define AUDD  128

__device__ __forceinline__ float wred_sum(float v){
  #pragma unroll
  for (int m = 32; m >= 1; m >>= 1) v += __shfl_xor(v, m, 64);
  return v;
}
__device__ __forceinline__ int wred_sumi(int v){
  #pragma unroll
  for (int m = 32; m >= 1; m >>= 1) v += __shfl_xor(v, m, 64);
  return v;
}
__device__ __forceinline__ float wred_max(float v){
  #pragma unroll
  for (int m = 32; m >= 1; m >>= 1) v = fmaxf(v, __shfl_xor(v, m, 64));
  return v;
}

// ---------------- merged front: type-bucket counts + edge-degree atomics + bstart ----------------
// grid covers E (largest). deg must be ZEROED before (memset); self-loop +1 added in the scan.
__global__ __launch_bounds__(256) void k_front(const int* __restrict__ ntype,
    const int* __restrict__ batch, const int* __restrict__ ei,
    int nN, int E, int B, int nblk,
    int* __restrict__ bcnt, int* __restrict__ deg, int* __restrict__ bstart){
  int b = blockIdx.x;
  int t = threadIdx.x;
  int i = b*256 + t;
  int lane = t & 63, w = t >> 6;
  // (a) type-bucket counts (blocks < nblk)
  int ty = (b < nblk && i < nN) ? ntype[i] : -1;
  __shared__ int wc[4][3];
  #pragma unroll
  for (int h = 0; h < 3; h++){
    unsigned long long m = __ballot(ty == h);
    if (lane == 0) wc[w][h] = __popcll(m);
  }
  __syncthreads();
  if (b < nblk && t < 3){
    int h = t;
    bcnt[h*nblk + b] = wc[0][h] + wc[1][h] + wc[2][h] + wc[3][h];
  }
  // (b) bstart boundary-detect (sorted batch)
  if (i < nN){
    int prev = (i == 0) ? -1 : batch[i-1];
    int cur  = batch[i];
    for (int bb = prev+1; bb <= cur; bb++) bstart[bb] = i;
  } else if (i == nN){
    int last = batch[nN-1];
    for (int bb = last+1; bb <= B; bb++) bstart[bb] = nN;
  }
  // (c) edge-degree atomics
  if (i < E) atomicAdd(&deg[ei[E + i]], 1);
}

// ---------------- bscan + afold merged (one block) ----------------
__global__ __launch_bounds__(1024) void k_bscan_afold(const int* __restrict__ bcnt, int nblk, int nN,
    int* __restrict__ boff, int* __restrict__ toff, int* __restrict__ tcnt,
    const float* __restrict__ W1, const float* __restrict__ a1s, const float* __restrict__ a1d,
    float* __restrict__ wfs, float* __restrict__ wfd){
  int t = threadIdx.x;
  // afold on t<256 (no barriers inside)
  if (t < 256){
    int k = t & 63, h = t >> 6;
    const float* wr = W1 + (size_t)k*256 + h*64;
    const float* as = a1s + h*64;
    const float* ad = a1d + h*64;
    float s = 0.f, d = 0.f;
    for (int c = 0; c < 64; c += 4){
      float4 wv = *reinterpret_cast<const float4*>(wr + c);
      float4 sa = *reinterpret_cast<const float4*>(as + c);
      float4 da = *reinterpret_cast<const float4*>(ad + c);
      s += wv.x*sa.x + wv.y*sa.y + wv.z*sa.z + wv.w*sa.w;
      d += wv.x*da.x + wv.y*da.y + wv.z*da.z + wv.w*da.w;
    }
    wfs[k*4 + h] = s;
    wfd[k*4 + h] = d;
  }
  // bscan
  __shared__ int s[2048];          // supports nblk*3 <= 2048
  int n3 = nblk*3;
  for (int i = t; i < n3; i += 1024) s[i] = bcnt[i];
  __syncthreads();
  if (t == 0){
    int run = 0;
    for (int i = 0; i < n3; i++){ int v = s[i]; s[i] = run; run += v; }
  }
  __syncthreads();
  for (int i = t; i < n3; i += 1024) boff[i] = s[i];
  if (t == 0){
    toff[0] = 0;         toff[1] = s[nblk];           toff[2] = s[2*nblk];
    tcnt[0] = s[nblk];   tcnt[1] = s[2*nblk]-s[nblk]; tcnt[2] = nN - s[2*nblk];
  }
}

__global__ __launch_bounds__(256) void k_bscatter(const int* __restrict__ ntype, int nN, int nblk,
                                                  const int* __restrict__ boff, int* __restrict__ order){
  int b = blockIdx.x;
  int i = b*256 + threadIdx.x;
  int lane = threadIdx.x & 63, w = threadIdx.x >> 6;
  int ty = (i < nN) ? ntype[i] : -1;
  __shared__ int wc[4][3];
  __shared__ int woff[4][3];
  unsigned long long masks[3];
  #pragma unroll
  for (int t = 0; t < 3; t++){
    masks[t] = __ballot(ty == t);
    if (lane == 0) wc[w][t] = __popcll(masks[t]);
  }
  __syncthreads();
  if (threadIdx.x < 3){
    int t = threadIdx.x, run = 0;
    #pragma unroll
    for (int ww = 0; ww < 4; ww++){ woff[ww][t] = run; run += wc[ww][t]; }
  }
  __syncthreads();
  if (ty >= 0){
    int r = __popcll(masks[ty] & ((1ULL << lane) - 1ULL));
    int pos = boff[ty*nblk + b] + woff[w][ty] + r;
    order[pos] = i;
  }
}

// ---------------- multi-block scan over (deg[i]+1) ----------------
__global__ __launch_bounds__(1024) void k_sumblk(const int* __restrict__ deg, int n,
                                                 int* __restrict__ bsum){
  int b = blockIdx.x;
  int i = b*1024 + threadIdx.x;
  int lane = threadIdx.x & 63, w = threadIdx.x >> 6;
  __shared__ int wsum[16];
  int v = (i < n) ? deg[i] + 1 : 0;     // +1 = self-loop
  v = wred_sumi(v);
  if (lane == 0) wsum[w] = v;
  __syncthreads();
  if (threadIdx.x == 0){
    int s = 0;
    #pragma unroll
    for (int k = 0; k < 16; k++) s += wsum[k];
    bsum[b] = s;
  }
}
__global__ void k_sumscan(const int* __restrict__ bsum, int nsb, int* __restrict__ bsoff){
  if (threadIdx.x == 0){
    int run = 0;
    for (int i = 0; i < nsb; i++){ bsoff[i] = run; run += bsum[i]; }
    bsoff[nsb] = run;
  }
}
__global__ __launch_bounds__(1024) void k_offw(int* __restrict__ deg, const int* __restrict__ bsoff,
                                               int n, int* __restrict__ off){
  int b = blockIdx.x;
  int i = b*1024 + threadIdx.x;
  int t = threadIdx.x, lane = t & 63, w = t >> 6;
  __shared__ int wsum[16];
  int v = (i < n) ? deg[i] + 1 : 0;     // +1 = self-loop
  int orig = v;
  #pragma unroll
  for (int o = 1; o < 64; o <<= 1){ int u = __shfl_up(v, o, 64); if (lane >= o) v += u; }
  if (lane == 63) wsum[w] = v;
  __syncthreads();
  if (t < 16){
    int xv = wsum[t];
    #pragma unroll
    for (int o = 1; o < 16; o <<= 1){ int u = __shfl_up(xv, o, 16); if (t >= o) xv += u; }
    wsum[t] = xv;
  }
  __syncthreads();
  int wbase = (w == 0) ? 0 : wsum[w-1];
  int e = bsoff[b] + v + wbase - orig;     // exclusive
  if (i < n){ off[i] = e; deg[i] = e; }    // deg now = pos (row start)
  if (b == 0 && t == 0) off[n] = bsoff[gridDim.x];
}
__global__ void k_scatter(const int* __restrict__ ei, int E, int nN,
                          int* __restrict__ pos, int* __restrict__ csr_src){
  int i = blockIdx.x*blockDim.x + threadIdx.x;
  int total = E + nN;
  if (i >= total) return;
  int s, d;
  if (i < E){ s = ei[i]; d = ei[E + i]; } else { s = i - E; d = s; }
  int p = atomicAdd(&pos[d], 1);
  csr_src[p] = s;
}

// ---------------- projection (64-node tile, conflict-free) + FUSED alpha1 epilogue ----------
__global__ __launch_bounds__(256) void k_projgemm(const float* __restrict__ x,
    const int* __restrict__ order, const int* __restrict__ toff, const int* __restrict__ tcnt,
    const float* __restrict__ Wt, const float* __restrict__ bt,
    const float* __restrict__ Wv, const float* __restrict__ bv,
    const float* __restrict__ Wa, const float* __restrict__ ba,
    const float* __restrict__ wfs, const float* __restrict__ wfd,
    float* __restrict__ h0, float* __restrict__ as1, float* __restrict__ ad1){
  int ty = blockIdx.y;
  int cnt = tcnt[ty];
  int tile = blockIdx.x;
  if (tile*64 >= cnt) return;
  const float* W; const float* bias; int dim;
  if (ty == 0)      { W = Wt; bias = bt; dim = TEXTD; }
  else if (ty == 1) { W = Wv; bias = bv; dim = VISD; }
  else              { W = Wa; bias = ba; dim = AUDD; }
  int off = toff[ty];

  __shared__ float xsT[64][68];
  __shared__ float ws [64][68];
  __shared__ int   nid[64];

  int t = threadIdx.x;
  if (t < 64){
    int idx = tile*64 + t;
    nid[t] = (idx < cnt) ? order[off + idx] : -1;
  }
  __syncthreads();

  int node_l = t & 63;
  int ndl = nid[node_l];
  const float* xrow = x + (size_t)(ndl < 0 ? 0 : ndl) * TEXTD;
  int wrow = t >> 2, wu = t & 3;
  int wvq  = t >> 6;
  int n0 = (t & 15)*4, c0 = (t >> 4)*4, qg = t >> 4;
  float acc[4][4] = {};

  for (int k0 = 0; k0 < dim; k0 += 64){
    __syncthreads();
    #pragma unroll
    for (int j = 0; j < 4; j++){
      int f4 = wvq*4 + j;
      float4 v = *reinterpret_cast<const float4*>(xrow + k0 + f4*4);
      xsT[f4*4+0][node_l] = v.x;
      xsT[f4*4+1][node_l] = v.y;
      xsT[f4*4+2][node_l] = v.z;
      xsT[f4*4+3][node_l] = v.w;
    }
    #pragma unroll
    for (int j = 0; j < 4; j++){
      int f4 = j*4 + wu;
      float4 v = *reinterpret_cast<const float4*>(W + (size_t)(k0 + wrow)*64 + f4*4);
      *reinterpret_cast<float4*>(&ws[wrow][f4*4]) = v;
    }
    __syncthreads();
    #pragma unroll 8
    for (int kk = 0; kk < 64; kk++){
      float4 xv = *reinterpret_cast<const float4*>(&xsT[kk][n0]);
      float4 wv = *reinterpret_cast<const float4*>(&ws[kk][c0]);
      float xa[4] = {xv.x, xv.y, xv.z, xv.w};
      float wb[4] = {wv.x, wv.y, wv.z, wv.w};
      #pragma unroll
      for (int i = 0; i < 4; i++)
        #pragma unroll
        for (int j = 0; j < 4; j++)
          acc[i][j] += xa[i] * wb[j];
    }
  }

  float4 b4 = *reinterpret_cast<const float4*>(bias + c0);
  float bb[4] = {b4.x, b4.y, b4.z, b4.w};
  #pragma unroll
  for (int i = 0; i < 4; i++){
    int nd = nid[n0 + i];
    if (nd >= 0){
      float4 o4 = make_float4(acc[i][0]+bb[0], acc[i][1]+bb[1], acc[i][2]+bb[2], acc[i][3]+bb[3]);
      *reinterpret_cast<float4*>(h0 + (size_t)nd*64 + c0) = o4;
    }
  }

  // -------- fused alpha1: as1/ad1 = (h0+b) @ wfs/wfd, reducing across 16 chan-groups --------
  __syncthreads();
  float* spart = &ws [0][0];                 // [node][qg][h]
  float* dpart = &xsT[0][0];
  float4 wsv[4], wdv[4];
  #pragma unroll
  for (int j = 0; j < 4; j++){
    wsv[j] = *reinterpret_cast<const float4*>(wfs + (c0+j)*4);
    wdv[j] = *reinterpret_cast<const float4*>(wfd + (c0+j)*4);
  }
  #pragma unroll
  for (int i = 0; i < 4; i++){
    float hv[4];
    #pragma unroll
    for (int j = 0; j < 4; j++) hv[j] = acc[i][j] + bb[j];
    float s0v = hv[0]*wsv[0].x + hv[1]*wsv[1].x + hv[2]*wsv[2].x + hv[3]*wsv[3].x;
    float s1v = hv[0]*wsv[0].y + hv[1]*wsv[1].y + hv[2]*wsv[2].y + hv[3]*wsv[3].y;
    float s2v = hv[0]*wsv[0].z + hv[1]*wsv[1].z + hv[2]*wsv[2].z + hv[3]*wsv[3].z;
    float s3v = hv[0]*wsv[0].w + hv[1]*wsv[1].w + hv[2]*wsv[2].w + hv[3]*wsv[3].w;
    float d0v = hv[0]*wdv[0].x + hv[1]*wdv[1].x + hv[2]*wdv[2].x + hv[3]*wdv[3].x;
    float d1v = hv[0]*wdv[0].y + hv[1]*wdv[1].y + hv[2]*wdv[2].y + hv[3]*wdv[3].y;
    float d2v = hv[0]*wdv[0].z + hv[1]*wdv[1].z + hv[2]*wdv[2].z + hv[3]*wdv[3].z;
    float d3v = hv[0]*wdv[0].w + hv[1]*wdv[1].w + hv[2]*wdv[2].w + hv[3]*wdv[3].w;
    int nidx = (n0 + i)*64 + qg*4;
    spart[nidx+0]=s0v; spart[nidx+1]=s1v; spart[nidx+2]=s2v; spart[nidx+3]=s3v;
    dpart[nidx+0]=d0v; dpart[nidx+1]=d1v; dpart[nidx+2]=d2v; dpart[nidx+3]=d3v;
  }
  __syncthreads();
  if (t < 64){
    int nd = nid[t];
    if (nd >= 0){
      float s[4] = {0,0,0,0}, d[4] = {0,0,0,0};
      #pragma unroll
      for (int g = 0; g < 16; g++){
        #pragma unroll
        for (int h = 0; h < 4; h++){
          s[h] += spart[t*64 + g*4 + h];
          d[h] += dpart[t*64 + g*4 + h];
        }
      }
      *reinterpret_cast<float4*>(as1 + (size_t)nd*4) = make_float4(s[0],s[1],s[2],s[3]);
      *reinterpret_cast<float4*>(ad1 + (size_t)nd*4) = make_float4(d[0],d[1],d[2],d[3]);
    }
  }
}

// ---------------- conv1 aggregate over h0: 4 waves/block, wave-private LDS, NO barriers -------
__global__ __launch_bounds__(256) void k_gat1z(const int* __restrict__ off, const int* __restrict__ srcs,
    const float* __restrict__ as1, const float* __restrict__ ad1,
    const float* __restrict__ h0, float* __restrict__ z, int nN){
  int w = threadIdx.x >> 6, L = threadIdx.x & 63;
  int n = blockIdx.x*4 + w;
  __shared__ int   s_src[4][64];
  __shared__ float s_p[4][64][4];
  if (n >= nN) return;
  int hL = L >> 4, c4 = (L & 15)*4;
  float ad[4];
  { float4 a = *reinterpret_cast<const float4*>(ad1 + (size_t)n*4);
    ad[0]=a.x; ad[1]=a.y; ad[2]=a.z; ad[3]=a.w; }
  int s0 = off[n], s1 = off[n+1];
  float m[4] = {-1e30f,-1e30f,-1e30f,-1e30f};
  float den[4] = {0.f,0.f,0.f,0.f};
  float4 acc = make_float4(0.f,0.f,0.f,0.f);
  for (int base = s0; base < s1; base += 64){
    int e = base + L;
    int cl = min(64, s1 - base);
    bool valid = (e < s1);
    int sv = 0; float v[4];
    if (valid){
      sv = srcs[e];
      float4 a = *reinterpret_cast<const float4*>(as1 + (size_t)sv*4);
      float av[4] = {a.x,a.y,a.z,a.w};
      #pragma unroll
      for (int h = 0; h < 4; h++){ float tt = av[h] + ad[h]; v[h] = (tt>0.f)?tt:0.2f*tt; }
    } else {
      #pragma unroll
      for (int h = 0; h < 4; h++) v[h] = -1e30f;
    }
    float sc[4], pv[4];
    #pragma unroll
    for (int h = 0; h < 4; h++){
      float cm = wred_max(v[h]);
      float mn = fmaxf(m[h], cm);
      sc[h] = __expf(m[h] - mn);
      m[h] = mn;
      float p = valid ? __expf(v[h] - mn) : 0.f;
      den[h] = den[h]*sc[h] + wred_sum(p);
      pv[h] = p;
    }
    { float s4 = sc[hL]; acc.x*=s4; acc.y*=s4; acc.z*=s4; acc.w*=s4; }
    if (valid){
      s_src[w][L] = sv;
      *reinterpret_cast<float4*>(&s_p[w][L][0]) = make_float4(pv[0],pv[1],pv[2],pv[3]);
    }
    #pragma unroll 4
    for (int e2 = 0; e2 < cl; e2++){
      int sr = s_src[w][e2];
      float pp = s_p[w][e2][hL];
      float4 hv = *reinterpret_cast<const float4*>(h0 + (size_t)sr*64 + c4);
      acc.x += pp*hv.x; acc.y += pp*hv.y; acc.z += pp*hv.z; acc.w += pp*hv.w;
    }
  }
  float dl = den[hL] + 1e-16f;
  *reinterpret_cast<float4*>(z + (size_t)n*256 + hL*64 + c4) =
      make_float4(acc.x/dl, acc.y/dl, acc.z/dl, acc.w/dl);
}

// ---------------- FUSED conv1-lin + conv2-lin:  h2 = ELU(z_q @ W1_q + b1) @ W2 ; alpha2 --------
__global__ __launch_bounds__(256) void k_fuse12(const float* __restrict__ z,
    const float* __restrict__ W1, const float* __restrict__ b1,
    const float* __restrict__ W2, const float* __restrict__ a2s, const float* __restrict__ a2d,
    float* __restrict__ h2, float* __restrict__ as2, float* __restrict__ ad2, int nN){
  int base = blockIdx.x*64;
  __shared__ float xsT[64][68];
  __shared__ float ws [64][68];
  __shared__ float sPart[16][64];
  __shared__ float dPart[16][64];

  int t = threadIdx.x;
  int row = t >> 2, fq = t & 3;
  int ndl = base + row; if (ndl >= nN) ndl = nN - 1;
  int n0 = (t & 15)*4, c0 = (t >> 4)*4, qg = t >> 4;
  float h2acc[4][4] = {};

  for (int q = 0; q < 4; q++){
    __syncthreads();
    {
      const float* zr = z + (size_t)ndl*256 + q*64;
      #pragma unroll
      for (int j = 0; j < 4; j++){
        int f4 = j*4 + fq;
        float4 v = *reinterpret_cast<const float4*>(zr + f4*4);
        xsT[f4*4+0][row] = v.x; xsT[f4*4+1][row] = v.y;
        xsT[f4*4+2][row] = v.z; xsT[f4*4+3][row] = v.w;
      }
    }
    #pragma unroll
    for (int j = 0; j < 4; j++){
      int f4 = j*4 + fq;
      float4 v = *reinterpret_cast<const float4*>(W1 + (size_t)row*256 + q*64 + f4*4);
      *reinterpret_cast<float4*>(&ws[row][f4*4]) = v;
    }
    __syncthreads();
    float racc[4][4] = {};
    #pragma unroll 8
    for (int k = 0; k < 64; k++){
      float4 xv = *reinterpret_cast<const float4*>(&xsT[k][n0]);
      float4 wv = *reinterpret_cast<const float4*>(&ws[k][c0]);
      float xa[4] = {xv.x, xv.y, xv.z, xv.w};
      float wb[4] = {wv.x, wv.y, wv.z, wv.w};
      #pragma unroll
      for (int i = 0; i < 4; i++)
        #pragma unroll
        for (int j = 0; j < 4; j++)
          racc[i][j] += xa[i] * wb[j];
    }
    {
      float4 b4 = *reinterpret_cast<const float4*>(b1 + q*64 + c0);
      float bb[4] = {b4.x, b4.y, b4.z, b4.w};
      #pragma unroll
      for (int i = 0; i < 4; i++)
        #pragma unroll
        for (int j = 0; j < 4; j++){
          float u = racc[i][j] + bb[j];
          racc[i][j] = (u > 0.f) ? u : expm1f(u);
        }
    }
    __syncthreads();
    #pragma unroll
    for (int i = 0; i < 4; i++)
      #pragma unroll
      for (int j = 0; j < 4; j++)
        xsT[c0+j][n0+i] = racc[i][j];
    #pragma unroll
    for (int j = 0; j < 4; j++){
      int f4 = j*4 + fq;
      float4 v = *reinterpret_cast<const float4*>(W2 + (size_t)(q*64 + row)*64 + f4*4);
      *reinterpret_cast<float4*>(&ws[row][f4*4]) = v;
    }
    __syncthreads();
    #pragma unroll 8
    for (int k = 0; k < 64; k++){
      float4 xv = *reinterpret_cast<const float4*>(&xsT[k][n0]);
      float4 wv = *reinterpret_cast<const float4*>(&ws[k][c0]);
      float xa[4] = {xv.x, xv.y, xv.z, xv.w};
      float wb[4] = {wv.x, wv.y, wv.z, wv.w};
      #pragma unroll
      for (int i = 0; i < 4; i++)
        #pragma unroll
        for (int j = 0; j < 4; j++)
          h2acc[i][j] += xa[i] * wb[j];
    }
  }

  float avs[4], avd[4];
  {
    float4 s4 = *reinterpret_cast<const float4*>(a2s + c0);
    float4 d4 = *reinterpret_cast<const float4*>(a2d + c0);
    avs[0]=s4.x; avs[1]=s4.y; avs[2]=s4.z; avs[3]=s4.w;
    avd[0]=d4.x; avd[1]=d4.y; avd[2]=d4.z; avd[3]=d4.w;
  }
  #pragma unroll
  for (int i = 0; i < 4; i++){
    int nd = base + n0 + i;
    float sp = h2acc[i][0]*avs[0] + h2acc[i][1]*avs[1] + h2acc[i][2]*avs[2] + h2acc[i][3]*avs[3];
    float dp = h2acc[i][0]*avd[0] + h2acc[i][1]*avd[1] + h2acc[i][2]*avd[2] + h2acc[i][3]*avd[3];
    sPart[qg][n0+i] = sp;
    dPart[qg][n0+i] = dp;
    if (nd < nN){
      float4 o4 = make_float4(h2acc[i][0], h2acc[i][1], h2acc[i][2], h2acc[i][3]);
      *reinterpret_cast<float4*>(h2 + (size_t)nd*64 + c0) = o4;
    }
  }
  __syncthreads();
  if (t < 64){
    int nd = base + t;
    if (nd < nN){
      float s = 0.f, d = 0.f;
      #pragma unroll
      for (int g = 0; g < 16; g++){ s += sPart[g][t]; d += dPart[g][t]; }
      as2[nd] = s;
      ad2[nd] = d;
    }
  }
}

// ---------------- conv2 aggregate + b2 -> g2[n][64] (no atomics; exec-mask-safe shfl) ----------
__global__ __launch_bounds__(256) void k_gat2v(const int* __restrict__ off, const int* __restrict__ srcs,
    const float* __restrict__ as2, const float* __restrict__ ad2,
    const float* __restrict__ h2, const float* __restrict__ b2,
    float* __restrict__ g2, int nN){
  int w = threadIdx.x >> 6, L = threadIdx.x & 63;
  int n = blockIdx.x*4 + w;
  if (n >= nN) return;
  int g = L >> 4, c4 = (L & 15)*4;
  float ad = ad2[n];
  int s0 = off[n], s1 = off[n+1];
  float m = -1e30f, den = 0.f;
  float4 acc = make_float4(0.f,0.f,0.f,0.f);
  for (int base = s0; base < s1; base += 64){
    int e = base + L;
    int cl = min(64, s1 - base);
    bool valid = (e < s1);
    int sv = 0; float v = -1e30f;
    if (valid){
      sv = srcs[e];
      float tt = as2[sv] + ad;
      v = (tt>0.f)?tt:0.2f*tt;
    }
    float cm = wred_max(v);
    float mn = fmaxf(m, cm);
    float sc = __expf(m - mn);
    m = mn;
    float p = valid ? __expf(v - mn) : 0.f;
    den = den*sc + wred_sum(p);
    acc.x*=sc; acc.y*=sc; acc.z*=sc; acc.w*=sc;
    int iters = (cl + 3) >> 2;          // wave-uniform trip count
    for (int it = 0; it < iters; ++it){
      int e2   = it*4 + g;
      int esrc = (e2 < cl) ? e2 : (cl - 1);   // clamp -> source lane always active
      int   sr = __shfl(sv, esrc, 64);
      float pp = __shfl(p,  esrc, 64);
      if (e2 < cl){
        float4 hv = *reinterpret_cast<const float4*>(h2 + (size_t)sr*64 + c4);
        acc.x += pp*hv.x; acc.y += pp*hv.y; acc.z += pp*hv.z; acc.w += pp*hv.w;
      }
    }
  }
  #pragma unroll
  for (int s = 16; s <= 32; s <<= 1){
    acc.x += __shfl_xor(acc.x, s, 64);
    acc.y += __shfl_xor(acc.y, s, 64);
    acc.z += __shfl_xor(acc.z, s, 64);
    acc.w += __shfl_xor(acc.w, s, 64);
  }
  float dl = den + 1e-16f;
  if (L < 16){
    float4 b4 = *reinterpret_cast<const float4*>(b2 + c4);
    float4 o4 = make_float4(acc.x/dl + b4.x, acc.y/dl + b4.y,
                            acc.z/dl + b4.z, acc.w/dl + b4.w);
    *reinterpret_cast<float4*>(g2 + (size_t)n*64 + c4) = o4;
  }
}

// ---------------- pool: out[b] = mean(g2 rows) @ Wl + bl ----------------
__global__ __launch_bounds__(64) void k_pool(const float* __restrict__ g2, const int* __restrict__ bstart,
    const float* __restrict__ Wl, const float* __restrict__ bl, float* __restrict__ out, int B){
  int b = blockIdx.x, c = threadIdx.x;
  int r0 = bstart[b], r1 = bstart[b+1];
  float s = 0.f;
  int i = r0;
  for (; i + 4 <= r1; i += 4){
    s += g2[(size_t)(i+0)*64 + c];
    s += g2[(size_t)(i+1)*64 + c];
    s += g2[(size_t)(i+2)*64 + c];
    s += g2[(size_t)(i+3)*64 + c];
  }
  for (; i < r1; i++) s += g2[(size_t)i*64 + c];
  float g = s / fmaxf((float)(r1 - r0), 1.f);
  float v = wred_sum(g * Wl[c]);
  if (c == 0) out[b] = v + bl[0];
}

extern "C" void kernel_launch(void* const* d_in, const int* in_sizes, int n_in,
                              void* d_out, int out_size, void* d_ws, size_t ws_size,
                              hipStream_t stream){
  const float* x    = (const float*)d_in[0];
  const int*   ntyp = (const int*)  d_in[1];
  const int*   ei   = (const int*)  d_in[2];
  const int*   batch= (const int*)  d_in[3];
  const float* Wt = (const float*)d_in[4];
  const float* bt = (const float*)d_in[5];
  const float* Wv = (const float*)d_in[6];
  const float* bv = (const float*)d_in[7];
  const float* Wa = (const float*)d_in[8];
  const float* ba = (const float*)d_in[9];
  const float* W1 = (const float*)d_in[10];
  const float* a1s= (const float*)d_in[11];
  const float* a1d= (const float*)d_in[12];
  const float* b1 = (const float*)d_in[13];
  const float* W2 = (const float*)d_in[14];
  const float* a2s= (const float*)d_in[15];
  const float* a2d= (const float*)d_in[16];
  const float* b2 = (const float*)d_in[17];
  const float* Wl = (const float*)d_in[18];
  const float* bl = (const float*)d_in[19];

  const int N = in_sizes[1];
  const int E = in_sizes[2] / 2;
  const int B = out_size;
  const int nblk = (N + 255)/256;
  const int nsb  = (N + 1023)/1024;

  char* ws = (char*)d_ws;
  size_t o = 0;
  auto alloc = [&](size_t bytes) -> void* {
    void* p = ws + o;
    o = (o + bytes + 255) & ~(size_t)255;
    return p;
  };
  int*   csr_off = (int*)  alloc((size_t)(N+1)*4);
  int*   pos     = (int*)  alloc((size_t)N*4);     // doubles as deg
  int*   csr_src = (int*)  alloc((size_t)(E+N)*4);
  float* as1     = (float*)alloc((size_t)N*4*4);
  float* ad1     = (float*)alloc((size_t)N*4*4);
  float* h0      = (float*)alloc((size_t)N*64*4);
  float* zbuf    = (float*)alloc((size_t)N*256*4);
  int*   bstart  = (int*)  alloc((size_t)(B+1)*4);
  int*   bcnt    = (int*)  alloc((size_t)nblk*3*4);
  int*   boff    = (int*)  alloc((size_t)nblk*3*4);
  int*   toff    = (int*)  alloc(3*4);
  int*   tcnt    = (int*)  alloc(3*4);
  int*   order   = (int*)  alloc((size_t)N*4);
  float* wfs     = (float*)alloc(256*4);
  float* wfd     = (float*)alloc(256*4);
  int*   bsum    = (int*)  alloc((size_t)nsb*4);
  int*   bsoff   = (int*)  alloc((size_t)(nsb+1)*4);
  // aliases: h2 reuses h0 (dead after k_gat1z); alpha2 reuses alpha1 (dead after k_gat1z);
  //          g2 reuses zbuf (dead after k_fuse12)
  float* h2  = h0;
  float* as2 = as1;
  float* ad2 = ad1;
  float* g2  = zbuf;

  // deg must be zero before edge atomics (self-loop +1 is added in the scan)
  hipMemsetAsync(pos, 0, (size_t)N*4, stream);

  // merged front: bucket counts + edge-degree atomics + bstart
  k_front<<<(E + 255)/256, 256, 0, stream>>>(ntyp, batch, ei, N, E, B, nblk, bcnt, pos, bstart);
  k_bscan_afold<<<1, 1024, 0, stream>>>(bcnt, nblk, N, boff, toff, tcnt, W1, a1s, a1d, wfs, wfd);
  k_bscatter<<<nblk, 256, 0, stream>>>(ntyp, N, nblk, boff, order);

  // CSR scan (over deg+1) + scatter
  k_sumblk  <<<nsb, 1024, 0, stream>>>(pos, N, bsum);
  k_sumscan <<<1, 64, 0, stream>>>(bsum, nsb, bsoff);
  k_offw    <<<nsb, 1024, 0, stream>>>(pos, bsoff, N, csr_off);
  k_scatter <<<(E + N + 255)/256, 256, 0, stream>>>(ei, E, N, pos, csr_src);

  // projection + fused alpha1 (64-node tiles; conflict-free stride-4 LDS)
  {
    dim3 g((N + 63)/64, 3);
    k_projgemm<<<g, 256, 0, stream>>>(x, order, toff, tcnt, Wt, bt, Wv, bv, Wa, ba,
                                      wfs, wfd, h0, as1, ad1);
  }

  // conv1 aggregate -> fused (per-head GEMM + ELU + lin2 + alpha2)
  k_gat1z <<<(N + 3)/4, 256, 0, stream>>>(csr_off, csr_src, as1, ad1, h0, zbuf, N);
  k_fuse12<<<(N + 63)/64, 256, 0, stream>>>(zbuf, W1, b1, W2, a2s, a2d, h2, as2, ad2, N);

  // conv2 + pooling
  k_gat2v<<<(N + 3)/4, 256, 0, stream>>>(csr_off, csr_src, as2, ad2, h2, b2, g2, N);
  k_pool<<<B, 64, 0, stream>>>(g2, bstart, Wl, bl, (float*)d_out, B);
}